// Round 3
// baseline (168.417 us; speedup 1.0000x reference)
//
#include <hip/hip_runtime.h>
#include <hip/hip_bf16.h>

// CumulativeLayerNorm: x [B=8, C=512, T=16000] f32.
// Pass 1: per-(b,t) column sums s1=Σ_c x, q=Σ_c x² (C split in 8 chunks, 4 blk/CU).
// Pass 2: per-b hierarchical scan over t (thread-serial 16 elems/thread): mean, istd.
// Pass 3: normalize, 2D grid (one (b,c) row per y-block), nt stores.
// Workspace (floats): s1p[8*B*T], qp[8*B*T], mean[B*T], istd[B*T]  (~9.2 MB).

constexpr int Bb = 8;
constexpr int Cc = 512;
constexpr int Tt = 16000;
constexpr int T4 = Tt / 4;      // 4000
constexpr int NCH = 8;          // c-chunks in pass 1
constexpr int CPC = Cc / NCH;   // 64
constexpr float EPSF = 1e-8f;

typedef float f32x4 __attribute__((ext_vector_type(4)));

// ---------------- Pass 1: column stats (float4 over t) ----------------
__global__ __launch_bounds__(256, 4)
void colstats_kernel(const float* __restrict__ x,
                     float* __restrict__ s1p, float* __restrict__ qp)
{
    const int t4 = blockIdx.x * 256 + threadIdx.x;
    const int b  = blockIdx.y;
    const int ch = blockIdx.z;
    if (t4 >= T4) return;

    const f32x4* xb = (const f32x4*)x + (size_t)(b * Cc + ch * CPC) * T4 + t4;

    f32x4 as0 = 0, as1 = 0, as2 = 0, as3 = 0;
    f32x4 aq0 = 0, aq1 = 0, aq2 = 0, aq3 = 0;

    #pragma unroll 1
    for (int c = 0; c < CPC; c += 8) {
        f32x4 v[8];
        #pragma unroll
        for (int u = 0; u < 8; ++u)
            v[u] = xb[(size_t)(c + u) * T4];
        as0 += v[0]; aq0 += v[0] * v[0];
        as1 += v[1]; aq1 += v[1] * v[1];
        as2 += v[2]; aq2 += v[2] * v[2];
        as3 += v[3]; aq3 += v[3] * v[3];
        as0 += v[4]; aq0 += v[4] * v[4];
        as1 += v[5]; aq1 += v[5] * v[5];
        as2 += v[6]; aq2 += v[6] * v[6];
        as3 += v[7]; aq3 += v[7] * v[7];
    }
    f32x4 s = (as0 + as1) + (as2 + as3);
    f32x4 q = (aq0 + aq1) + (aq2 + aq3);

    const int oidx = (ch * Bb + b) * T4 + t4;
    ((f32x4*)s1p)[oidx] = s;
    ((f32x4*)qp)[oidx]  = q;
}

// ---------------- Pass 2: per-batch scan, thread-serial 16/thread ----------------
#define SCAN_THREADS 1024

__device__ __forceinline__ float block_exscan(float val, int lane, int wave, float* lds)
{
    float sc = val;
    #pragma unroll
    for (int off = 1; off < 64; off <<= 1) {
        float n = __shfl_up(sc, off, 64);
        if (lane >= off) sc += n;
    }
    __syncthreads();                 // lds safe to overwrite (reuse across calls)
    if (lane == 63) lds[wave] = sc;
    __syncthreads();
    float pre = 0.f;
    #pragma unroll
    for (int w = 0; w < SCAN_THREADS / 64; ++w)
        if (w < wave) pre += lds[w];
    return pre + sc - val;           // exclusive prefix of this thread's val
}

__global__ __launch_bounds__(SCAN_THREADS)
void scan_kernel(const float* __restrict__ s1p, const float* __restrict__ qp,
                 float* __restrict__ meang, float* __restrict__ istdg)
{
    __shared__ float lds[SCAN_THREADS / 64];
    const int b    = blockIdx.x;
    const int tid  = threadIdx.x;
    const int lane = tid & 63;
    const int wave = tid >> 6;
    const float Cf = (float)Cc;

    const bool valid = tid < (Tt / 16);   // 1000 threads exactly cover T

    float s1v[16], qv[16];
    if (valid) {
        #pragma unroll
        for (int g = 0; g < 4; ++g) {
            f32x4 a = 0, qq = 0;
            #pragma unroll
            for (int ch = 0; ch < NCH; ++ch) {
                const int idx = (ch * Bb + b) * T4 + tid * 4 + g;
                a  += ((const f32x4*)s1p)[idx];
                qq += ((const f32x4*)qp)[idx];
            }
            s1v[4*g+0] = a.x; s1v[4*g+1] = a.y; s1v[4*g+2] = a.z; s1v[4*g+3] = a.w;
            qv[4*g+0] = qq.x; qv[4*g+1] = qq.y; qv[4*g+2] = qq.z; qv[4*g+3] = qq.w;
        }
    } else {
        #pragma unroll
        for (int i = 0; i < 16; ++i) { s1v[i] = 0.f; qv[i] = 0.f; }
    }

    // ---- scan of s1 ----
    float lsum = 0.f;
    #pragma unroll
    for (int i = 0; i < 16; ++i) lsum += s1v[i];
    const float base1 = block_exscan(lsum, lane, wave, lds);

    // serial walk: mean per element, s2 per element (stored into qv)
    float mean_r[16];
    float l2 = 0.f;
    {
        float cs = base1;
        #pragma unroll
        for (int i = 0; i < 16; ++i) {
            cs += s1v[i];
            const int t = tid * 16 + i;
            const float cnt = Cf * (float)(t + 1);
            const float mn = cs / cnt;
            mean_r[i] = mn;
            const float s2 = qv[i] - 2.f * mn * s1v[i] + Cf * mn * mn;
            qv[i] = s2;
            l2 += s2;
        }
    }
    if (!valid) l2 = 0.f;

    // ---- scan of s2 ----
    const float base2 = block_exscan(l2, lane, wave, lds);

    if (valid) {
        float cv = base2;
        float istd_r[16];
        #pragma unroll
        for (int i = 0; i < 16; ++i) {
            cv += qv[i];
            const int t = tid * 16 + i;
            const float cnt = Cf * (float)(t + 1);
            const float var = cv / cnt;
            istd_r[i] = rsqrtf(var + EPSF);
        }
        f32x4* mo = (f32x4*)(meang + (size_t)b * Tt) + tid * 4;
        f32x4* io = (f32x4*)(istdg + (size_t)b * Tt) + tid * 4;
        #pragma unroll
        for (int g = 0; g < 4; ++g) {
            f32x4 m, s;
            m.x = mean_r[4*g+0]; m.y = mean_r[4*g+1]; m.z = mean_r[4*g+2]; m.w = mean_r[4*g+3];
            s.x = istd_r[4*g+0]; s.y = istd_r[4*g+1]; s.z = istd_r[4*g+2]; s.w = istd_r[4*g+3];
            mo[g] = m;
            io[g] = s;
        }
    }
}

// ---------------- Pass 3: normalize (2D grid, one (b,c) row per y-block) ----------------
__global__ __launch_bounds__(256)
void normalize_kernel(const f32x4* __restrict__ x4,
                      const float* __restrict__ meang,
                      const float* __restrict__ istdg,
                      const float* __restrict__ gamma,
                      const float* __restrict__ beta,
                      f32x4* __restrict__ out4)
{
    const int bc = blockIdx.y;                // 0..B*C-1
    const int c  = bc & (Cc - 1);
    const int b  = bc >> 9;                   // Cc = 512 = 2^9

    const f32x4* xr = x4 + (size_t)bc * T4;
    f32x4* outr     = out4 + (size_t)bc * T4;
    const f32x4* mr = (const f32x4*)(meang + (size_t)b * Tt);
    const f32x4* sr = (const f32x4*)(istdg + (size_t)b * Tt);

    const float g  = gamma[c];
    const float be = beta[c];

    #pragma unroll
    for (int it = 0; it < 4; ++it) {
        const int t4 = it * 1024 + blockIdx.x * 256 + threadIdx.x;
        if (t4 < T4) {
            const f32x4 xv = xr[t4];
            const f32x4 m4 = mr[t4];
            const f32x4 s4 = sr[t4];
            const f32x4 o = (xv - m4) * s4 * g + be;
            __builtin_nontemporal_store(o, &outr[t4]);
        }
    }
}

extern "C" void kernel_launch(void* const* d_in, const int* in_sizes, int n_in,
                              void* d_out, int out_size, void* d_ws, size_t ws_size,
                              hipStream_t stream) {
    const float* x     = (const float*)d_in[0];
    const float* gamma = (const float*)d_in[1];
    const float* beta  = (const float*)d_in[2];
    float* out = (float*)d_out;

    float* ws   = (float*)d_ws;
    float* s1p  = ws;                                  // NCH*B*T
    float* qp   = ws + (size_t)NCH * Bb * Tt;          // NCH*B*T
    float* mean = ws + (size_t)2 * NCH * Bb * Tt;      // B*T
    float* istd = mean + (size_t)Bb * Tt;              // B*T

    // Pass 1: column stats (1024 blocks = 4/CU, 16 waves/CU)
    dim3 g1((T4 + 255) / 256, Bb, NCH);
    colstats_kernel<<<g1, 256, 0, stream>>>(x, s1p, qp);

    // Pass 2: scan (one block per batch)
    scan_kernel<<<Bb, SCAN_THREADS, 0, stream>>>(s1p, qp, mean, istd);

    // Pass 3: normalize
    dim3 g3(4, Bb * Cc);
    normalize_kernel<<<g3, 256, 0, stream>>>(
        (const f32x4*)x, mean, istd, gamma, beta, (f32x4*)out);
}

// Round 4
// 139.615 us; speedup vs baseline: 1.2063x; 1.2063x over previous
//
#include <hip/hip_runtime.h>
#include <hip/hip_bf16.h>

// CumulativeLayerNorm: x [B=8, C=512, T=16000] f32.
// K1: per-(b,t) partial column sums over NCH=4 channel chunks (512 blocks).
// K2: fold NCH partials -> s1[B*T], q[B*T]  (wide grid, cheap).
// K3: per-b hierarchical scan over t (thread-serial 16/thread): mean, istd.
// K4: normalize, reverse grid-stride (L3 reuse of x) + nontemporal stores.
// Workspace (floats): s1p[4*B*T], qp[4*B*T], s1[B*T], q[B*T], mean[B*T], istd[B*T].

constexpr int Bb = 8;
constexpr int Cc = 512;
constexpr int Tt = 16000;
constexpr int T4 = Tt / 4;      // 4000
constexpr int NCH = 4;          // c-chunks in K1
constexpr int CPC = Cc / NCH;   // 128
constexpr float EPSF = 1e-8f;

typedef float f32x4 __attribute__((ext_vector_type(4)));

// ---------------- K1: partial column stats (float4 over t) ----------------
__global__ __launch_bounds__(256)
void colstats_kernel(const float* __restrict__ x,
                     float* __restrict__ s1p, float* __restrict__ qp)
{
    const int t4 = blockIdx.x * 256 + threadIdx.x;
    const int b  = blockIdx.y;
    const int ch = blockIdx.z;
    if (t4 >= T4) return;

    const f32x4* xb = (const f32x4*)x + (size_t)(b * Cc + ch * CPC) * T4 + t4;

    f32x4 as0 = 0, as1 = 0, as2 = 0, as3 = 0;
    f32x4 aq0 = 0, aq1 = 0, aq2 = 0, aq3 = 0;

    #pragma unroll 1
    for (int c = 0; c < CPC; c += 8) {
        f32x4 v[8];
        #pragma unroll
        for (int u = 0; u < 8; ++u)
            v[u] = xb[(size_t)(c + u) * T4];
        as0 += v[0]; aq0 += v[0] * v[0];
        as1 += v[1]; aq1 += v[1] * v[1];
        as2 += v[2]; aq2 += v[2] * v[2];
        as3 += v[3]; aq3 += v[3] * v[3];
        as0 += v[4]; aq0 += v[4] * v[4];
        as1 += v[5]; aq1 += v[5] * v[5];
        as2 += v[6]; aq2 += v[6] * v[6];
        as3 += v[7]; aq3 += v[7] * v[7];
    }
    f32x4 s = (as0 + as1) + (as2 + as3);
    f32x4 q = (aq0 + aq1) + (aq2 + aq3);

    const int oidx = (ch * Bb + b) * T4 + t4;
    ((f32x4*)s1p)[oidx] = s;
    ((f32x4*)qp)[oidx]  = q;
}

// ---------------- K2: fold NCH partials ----------------
__global__ __launch_bounds__(256)
void reduce_kernel(const float* __restrict__ s1p, const float* __restrict__ qp,
                   float* __restrict__ s1, float* __restrict__ q)
{
    const int i = blockIdx.x * 256 + threadIdx.x;   // 0 .. B*T4-1 (f32x4 index)
    if (i >= Bb * T4) return;
    f32x4 a = 0, qq = 0;
    #pragma unroll
    for (int ch = 0; ch < NCH; ++ch) {
        a  += ((const f32x4*)s1p)[(size_t)ch * Bb * T4 + i];
        qq += ((const f32x4*)qp)[(size_t)ch * Bb * T4 + i];
    }
    ((f32x4*)s1)[i] = a;
    ((f32x4*)q)[i]  = qq;
}

// ---------------- K3: per-batch scan, thread-serial 16/thread ----------------
#define SCAN_THREADS 1024

__device__ __forceinline__ float block_exscan(float val, int lane, int wave, float* lds)
{
    float sc = val;
    #pragma unroll
    for (int off = 1; off < 64; off <<= 1) {
        float n = __shfl_up(sc, off, 64);
        if (lane >= off) sc += n;
    }
    __syncthreads();                 // lds safe to overwrite (reuse across calls)
    if (lane == 63) lds[wave] = sc;
    __syncthreads();
    float pre = 0.f;
    #pragma unroll
    for (int w = 0; w < SCAN_THREADS / 64; ++w)
        if (w < wave) pre += lds[w];
    return pre + sc - val;           // exclusive prefix of this thread's val
}

__global__ __launch_bounds__(SCAN_THREADS)
void scan_kernel(const float* __restrict__ s1g, const float* __restrict__ qg,
                 float* __restrict__ meang, float* __restrict__ istdg)
{
    __shared__ float lds[SCAN_THREADS / 64];
    const int b    = blockIdx.x;
    const int tid  = threadIdx.x;
    const int lane = tid & 63;
    const int wave = tid >> 6;
    const float Cf = (float)Cc;

    const bool valid = tid < (Tt / 16);   // 1000 threads exactly cover T

    float s1v[16], qv[16];
    if (valid) {
        #pragma unroll
        for (int g = 0; g < 4; ++g) {
            const int idx = b * T4 + tid * 4 + g;
            const f32x4 a  = ((const f32x4*)s1g)[idx];
            const f32x4 qq = ((const f32x4*)qg)[idx];
            s1v[4*g+0] = a.x; s1v[4*g+1] = a.y; s1v[4*g+2] = a.z; s1v[4*g+3] = a.w;
            qv[4*g+0] = qq.x; qv[4*g+1] = qq.y; qv[4*g+2] = qq.z; qv[4*g+3] = qq.w;
        }
    } else {
        #pragma unroll
        for (int i = 0; i < 16; ++i) { s1v[i] = 0.f; qv[i] = 0.f; }
    }

    // ---- scan of s1 ----
    float lsum = 0.f;
    #pragma unroll
    for (int i = 0; i < 16; ++i) lsum += s1v[i];
    const float base1 = block_exscan(lsum, lane, wave, lds);

    // serial walk: mean per element, s2 per element (stored into qv)
    float mean_r[16];
    float l2 = 0.f;
    {
        float cs = base1;
        #pragma unroll
        for (int i = 0; i < 16; ++i) {
            cs += s1v[i];
            const int t = tid * 16 + i;
            const float cnt = Cf * (float)(t + 1);
            const float mn = cs / cnt;
            mean_r[i] = mn;
            const float s2 = qv[i] - 2.f * mn * s1v[i] + Cf * mn * mn;
            qv[i] = s2;
            l2 += s2;
        }
    }
    if (!valid) l2 = 0.f;

    // ---- scan of s2 ----
    const float base2 = block_exscan(l2, lane, wave, lds);

    if (valid) {
        float cv = base2;
        float istd_r[16];
        #pragma unroll
        for (int i = 0; i < 16; ++i) {
            cv += qv[i];
            const int t = tid * 16 + i;
            const float cnt = Cf * (float)(t + 1);
            const float var = cv / cnt;
            istd_r[i] = rsqrtf(var + EPSF);
        }
        f32x4* mo = (f32x4*)(meang + (size_t)b * Tt) + tid * 4;
        f32x4* io = (f32x4*)(istdg + (size_t)b * Tt) + tid * 4;
        #pragma unroll
        for (int g = 0; g < 4; ++g) {
            f32x4 m, s;
            m.x = mean_r[4*g+0]; m.y = mean_r[4*g+1]; m.z = mean_r[4*g+2]; m.w = mean_r[4*g+3];
            s.x = istd_r[4*g+0]; s.y = istd_r[4*g+1]; s.z = istd_r[4*g+2]; s.w = istd_r[4*g+3];
            mo[g] = m;
            io[g] = s;
        }
    }
}

// ---------------- K4: normalize (reverse order, nt stores) ----------------
__global__ __launch_bounds__(256)
void normalize_kernel(const f32x4* __restrict__ x4,
                      const float* __restrict__ meang,
                      const float* __restrict__ istdg,
                      const float* __restrict__ gamma,
                      const float* __restrict__ beta,
                      f32x4* __restrict__ out4)
{
    constexpr int n4 = Bb * Cc * T4;           // 16,384,000 (fits int)
    const int gtid   = blockIdx.x * 256 + threadIdx.x;
    const int stride = gridDim.x * 256;
    const int nloop  = (n4 + stride - 1) / stride;

    // Reverse sweep: K1 just streamed x forward, so the TAIL of x is
    // L3-resident (262MB vs 256MB L3). Reading backward turns the re-read
    // into mostly L3 hits instead of LRU cyclic thrash. Non-temporal out
    // stores keep x resident.
    for (int k = nloop - 1; k >= 0; --k) {
        const int i = k * stride + gtid;
        if (i >= n4) continue;
        const int t4 = i % T4;
        const int bc = i / T4;
        const int c  = bc & (Cc - 1);
        const int b  = bc >> 9;                // Cc = 512 = 2^9

        const f32x4 xv = x4[i];
        const f32x4 m4 = *(const f32x4*)(meang + (size_t)b * Tt + t4 * 4);
        const f32x4 s4 = *(const f32x4*)(istdg + (size_t)b * Tt + t4 * 4);
        const float g  = gamma[c];
        const float be = beta[c];

        const f32x4 o = (xv - m4) * s4 * g + be;
        __builtin_nontemporal_store(o, &out4[i]);
    }
}

extern "C" void kernel_launch(void* const* d_in, const int* in_sizes, int n_in,
                              void* d_out, int out_size, void* d_ws, size_t ws_size,
                              hipStream_t stream) {
    const float* x     = (const float*)d_in[0];
    const float* gamma = (const float*)d_in[1];
    const float* beta  = (const float*)d_in[2];
    float* out = (float*)d_out;

    float* ws   = (float*)d_ws;
    float* s1p  = ws;                                  // NCH*B*T
    float* qp   = s1p + (size_t)NCH * Bb * Tt;         // NCH*B*T
    float* s1   = qp  + (size_t)NCH * Bb * Tt;         // B*T
    float* q    = s1  + (size_t)Bb * Tt;               // B*T
    float* mean = q   + (size_t)Bb * Tt;               // B*T
    float* istd = mean + (size_t)Bb * Tt;              // B*T

    // K1: partial column stats (512 blocks = 2/CU)
    dim3 g1((T4 + 255) / 256, Bb, NCH);
    colstats_kernel<<<g1, 256, 0, stream>>>(x, s1p, qp);

    // K2: fold partials (125 blocks exactly cover B*T4)
    reduce_kernel<<<(Bb * T4 + 255) / 256, 256, 0, stream>>>(s1p, qp, s1, q);

    // K3: scan (one block per batch)
    scan_kernel<<<Bb, SCAN_THREADS, 0, stream>>>(s1, q, mean, istd);

    // K4: normalize (reverse)
    normalize_kernel<<<4096, 256, 0, stream>>>(
        (const f32x4*)x, mean, istd, gamma, beta, (f32x4*)out);
}

// Round 5
// 97.380 us; speedup vs baseline: 1.7295x; 1.4337x over previous
//
#include <hip/hip_runtime.h>
#include <hip/hip_bf16.h>

// CumulativeLayerNorm fused single-pass: x [B=8, C=512, T=16000] f32.
// One block per (batch b, t-chunk of 128). Block holds its 512x128 x-tile in
// REGISTERS (1024 thr x 16 f32x4), computes column sums, resolves the global
// cumulative dependency via decoupled-lookback aggregates (fixed-order tree
// sum => deterministic), then normalizes from registers. x is read ONCE.
// Workspace: W1[1000] + W2[1000] u64 {flag,val} words (memset to 0 each launch).

constexpr int Bb = 8;
constexpr int Cc = 512;
constexpr int Tt = 16000;
constexpr int T4 = Tt / 4;          // 4000
constexpr int TCH = 128;            // t per chunk
constexpr int T4CH = TCH / 4;       // 32
constexpr int NCHK = Tt / TCH;      // 125
constexpr float EPSF = 1e-8f;

typedef float f32x4 __attribute__((ext_vector_type(4)));

__device__ __forceinline__ unsigned long long pack_av(float v) {
    return (1ull << 32) | (unsigned long long)__float_as_uint(v);
}

// Sum aggregates W[b-chain][0..k-1] in a FIXED order (64-lane slice + xor tree)
// -> deterministic across replays. Spins until each predecessor has published.
__device__ __forceinline__ float lookback_sum(const unsigned long long* W,
                                              int chain_base, int k, int lane)
{
    float carry = 0.f;
    #pragma unroll 1
    for (int base = 0; base < k; base += 64) {
        const int j = base + lane;
        float v = 0.f;
        if (j < k) {
            unsigned long long w;
            for (;;) {
                w = __hip_atomic_load(&W[chain_base + j], __ATOMIC_RELAXED,
                                      __HIP_MEMORY_SCOPE_AGENT);
                if (w >> 32) break;
                __builtin_amdgcn_s_sleep(1);
            }
            v = __uint_as_float((unsigned)w);
        }
        #pragma unroll
        for (int m = 1; m < 64; m <<= 1) v += __shfl_xor(v, m, 64);
        carry += v;
    }
    return carry;
}

__global__ __launch_bounds__(1024)
void fused_cln_kernel(const float* __restrict__ x,
                      const float* __restrict__ gamma,
                      const float* __restrict__ beta,
                      float* __restrict__ out,
                      unsigned long long* __restrict__ W1,
                      unsigned long long* __restrict__ W2)
{
    const int bid = blockIdx.x;
    const int k = bid >> 3;          // chunk index 0..124 (k-major => chains advance together)
    const int b = bid & 7;
    const int tid = threadIdx.x;
    const int c_sub = tid >> 5;      // 0..31
    const int t4s   = tid & 31;      // 0..31

    __shared__ float gam[Cc], bet[Cc];
    if (tid < Cc) { gam[tid] = gamma[tid]; bet[tid] = beta[tid]; }

    // ---------- phase A: load tile into registers, per-thread partial sums ----------
    const f32x4* xb = (const f32x4*)x + ((size_t)(b * Cc + c_sub)) * T4 + k * T4CH + t4s;
    f32x4 xr[16];
    #pragma unroll
    for (int r = 0; r < 16; ++r) xr[r] = xb[(size_t)r * 32 * T4];

    f32x4 ps = 0, pq = 0;
    #pragma unroll
    for (int r = 0; r < 16; ++r) { ps += xr[r]; pq += xr[r] * xr[r]; }

    __shared__ f32x4 red_s[32][32];
    __shared__ f32x4 red_q[32][32];
    red_s[c_sub][t4s] = ps;
    red_q[c_sub][t4s] = pq;
    __syncthreads();
    #pragma unroll
    for (int s = 16; s > 0; s >>= 1) {
        if (c_sub < s) {
            red_s[c_sub][t4s] += red_s[c_sub + s][t4s];
            red_q[c_sub][t4s] += red_q[c_sub + s][t4s];
        }
        __syncthreads();
    }

    // ---------- phase B: wave 0 scans the 128 t's + global lookback ----------
    __shared__ f32x4 mean_l[32], istd_l[32];

    if (tid < 64) {
        const int lane = tid;
        const bool act = lane < 32;
        const int chain = b * NCHK;

        const f32x4 sv = act ? red_s[0][lane] : (f32x4)0.f;
        const f32x4 qv = act ? red_q[0][lane] : (f32x4)0.f;

        // in-lane inclusive prefix over this lane's 4 t's
        const float c0 = sv.x, c1 = c0 + sv.y, c2 = c1 + sv.z, c3 = c2 + sv.w;
        float lsum = act ? c3 : 0.f;
        float sc = lsum;
        #pragma unroll
        for (int off = 1; off < 64; off <<= 1) {
            const float n = __shfl_up(sc, off, 64);
            if (lane >= off) sc += n;
        }
        const float total1 = __shfl(sc, 63, 64);   // lanes>=32 contribute 0
        const float ex1 = sc - lsum;

        if (lane == 0)
            __hip_atomic_store(&W1[chain + k], pack_av(total1), __ATOMIC_RELAXED,
                               __HIP_MEMORY_SCOPE_AGENT);
        const float carry1 = lookback_sum(W1, chain, k, lane);

        // counts and means for this lane's 4 t's
        const float t0f = (float)(k * TCH + lane * 4);
        f32x4 cnt;
        cnt.x = (float)Cc * (t0f + 1.f);
        cnt.y = (float)Cc * (t0f + 2.f);
        cnt.z = (float)Cc * (t0f + 3.f);
        cnt.w = (float)Cc * (t0f + 4.f);

        f32x4 cs1;
        cs1.x = carry1 + ex1 + c0;
        cs1.y = carry1 + ex1 + c1;
        cs1.z = carry1 + ex1 + c2;
        cs1.w = carry1 + ex1 + c3;
        const f32x4 mn = cs1 / cnt;
        if (act) mean_l[lane] = mn;

        // residual second moment per t (exactly the prior rounds' formula)
        f32x4 s2 = qv - 2.f * mn * sv + (float)Cc * mn * mn;
        if (!act) s2 = 0.f;

        const float d0 = s2.x, d1 = d0 + s2.y, d2 = d1 + s2.z, d3 = d2 + s2.w;
        float lsum2 = act ? d3 : 0.f;
        float sc2 = lsum2;
        #pragma unroll
        for (int off = 1; off < 64; off <<= 1) {
            const float n = __shfl_up(sc2, off, 64);
            if (lane >= off) sc2 += n;
        }
        const float total2 = __shfl(sc2, 63, 64);
        const float ex2 = sc2 - lsum2;

        if (lane == 0)
            __hip_atomic_store(&W2[chain + k], pack_av(total2), __ATOMIC_RELAXED,
                               __HIP_MEMORY_SCOPE_AGENT);
        const float carry2 = lookback_sum(W2, chain, k, lane);

        if (act) {
            f32x4 cs2;
            cs2.x = carry2 + ex2 + d0;
            cs2.y = carry2 + ex2 + d1;
            cs2.z = carry2 + ex2 + d2;
            cs2.w = carry2 + ex2 + d3;
            const f32x4 var = cs2 / cnt;
            f32x4 is;
            is.x = rsqrtf(var.x + EPSF);
            is.y = rsqrtf(var.y + EPSF);
            is.z = rsqrtf(var.z + EPSF);
            is.w = rsqrtf(var.w + EPSF);
            istd_l[lane] = is;
        }
    }
    __syncthreads();

    // ---------- phase C: normalize from registers, stream out ----------
    const f32x4 m4 = mean_l[t4s];
    const f32x4 s4 = istd_l[t4s];
    f32x4* ob = (f32x4*)out + ((size_t)(b * Cc + c_sub)) * T4 + k * T4CH + t4s;
    #pragma unroll
    for (int r = 0; r < 16; ++r) {
        const int c = c_sub + 32 * r;
        const float g  = gam[c];
        const float be = bet[c];
        const f32x4 sg   = s4 * g;
        const f32x4 off4 = be - m4 * sg;
        __builtin_nontemporal_store(xr[r] * sg + off4, &ob[(size_t)r * 32 * T4]);
    }
}

extern "C" void kernel_launch(void* const* d_in, const int* in_sizes, int n_in,
                              void* d_out, int out_size, void* d_ws, size_t ws_size,
                              hipStream_t stream) {
    const float* x     = (const float*)d_in[0];
    const float* gamma = (const float*)d_in[1];
    const float* beta  = (const float*)d_in[2];
    float* out = (float*)d_out;

    unsigned long long* W1 = (unsigned long long*)d_ws;
    unsigned long long* W2 = W1 + (size_t)Bb * NCHK;

    // clear lookback state every launch (ws is NOT re-poisoned between replays)
    hipMemsetAsync(d_ws, 0, 2 * (size_t)Bb * NCHK * sizeof(unsigned long long), stream);

    fused_cln_kernel<<<Bb * NCHK, 1024, 0, stream>>>(x, gamma, beta, out, W1, W2);
}